// Round 3
// baseline (130.713 us; speedup 1.0000x reference)
//
#include <hip/hip_runtime.h>

typedef unsigned int uint32;
typedef unsigned short ushort;

typedef __bf16  bf16x8   __attribute__((ext_vector_type(8)));
typedef float   f32x4    __attribute__((ext_vector_type(4)));
typedef ushort  ushort4v __attribute__((ext_vector_type(4)));

#define K_CODES 1024
#define CDIM    64
#define HWALL   4096      // H*W
#define CHW     262144    // CDIM*HWALL
#define TROWS   128       // z-rows per tile (2 tiles per block)

__device__ __forceinline__ ushort f2bf(float f) {
    uint32 u = __builtin_bit_cast(uint32, f);
    u += 0x7FFFu + ((u >> 16) & 1u);   // RNE
    return (ushort)(u >> 16);
}

// Pass 0 (tiny, coalesced): codebook fp32 -> bf16 row-major + negbias[k] =
// -0.5*||e_k||^2. Also zeroes the loss cell out[0].
__global__ __launch_bounds__(256) void prep_kernel(const float* __restrict__ cb,
                                                   ushort* __restrict__ cbb,
                                                   float* __restrict__ negbias,
                                                   float* __restrict__ out) {
    int t = threadIdx.x;
    if (blockIdx.x == 0 && t == 0) out[0] = 0.f;
    int k = blockIdx.x * 4 + (t >> 6);
    int c = t & 63;
    float v = cb[k * 64 + c];
    cbb[k * 64 + c] = f2bf(v);
    float s = v * v;
    #pragma unroll
    for (int d = 1; d < 64; d <<= 1) s += __shfl_xor(s, d, 64);
    if (c == 0) negbias[k] = -0.5f * s;
}

// Main: 256 blocks (1/CU) x 1024 threads (16 waves), two 128-row tiles,
// software-pipelined. R12: swapped MFMA operands (codes in acc-reg dim,
// argmax mostly in-register). R13 change: NONTEMPORAL memory ops for the
// streaming data -- z is read exactly once and out is written exactly once,
// so neither should allocate in L2/MALL. R2 counters showed 251 MB HBM
// traffic/dispatch (5x fetch, 9.6x write amplification vs the 34 MB ideal)
// with all pipes idle: the kernel is bound by write-allocate/eviction churn,
// not by compute, LDS, or useful bandwidth. Codebook gather stays cached.
__global__ __launch_bounds__(1024, 4) void vq_kernel(const float* __restrict__ z,
                                                     const ushort* __restrict__ cbb,
                                                     const float* __restrict__ negbias,
                                                     float* __restrict__ out) {
    __shared__ __align__(16) ushort Abf[TROWS * 72];  // 18 KB A-tile, pitch 72
    __shared__ float partial[16][TROWS];              // 8 KB packed argmax keys
    __shared__ float loss_acc;

    const int t   = threadIdx.x;
    const int blk = blockIdx.x;
    const int b   = blk >> 4;
    const int hw0 = (blk & 15) << 8;          // 256 rows per block
    const int zoff0 = b * CHW + hw0;

    if (t == 0) loss_acc = 0.f;

    const int r  = t & 127;    // z-row within tile (lanes consecutive -> coalesced)
    const int cg = t >> 7;     // c-group 0..7
    const int w  = t >> 6;     // wave 0..15: owns codes [w*64, +64)
    const int l  = t & 63;
    const int m  = l & 15;
    const int q  = l >> 4;

    // ---- issue tile-0 z loads (deepest dep); NT: streamed once, don't cache ----
    float z0v[8];
    #pragma unroll
    for (int j = 0; j < 8; ++j)
        z0v[j] = __builtin_nontemporal_load(&z[zoff0 + (cg * 8 + j) * HWALL + r]);

    // ---- load this wave's codebook slice into registers (once, from bf16) ----
    bf16x8 Bv[4][2];
    f32x4  nbv[4];
    #pragma unroll
    for (int j = 0; j < 4; ++j) {
        int col = (((w << 2) + j) << 4) + m;
        Bv[j][0] = *(const bf16x8*)&cbb[(col << 6) + (q << 3)];
        Bv[j][1] = *(const bf16x8*)&cbb[(col << 6) + 32 + (q << 3)];
        nbv[j] = *(const f32x4*)&negbias[((((w << 2) + j) << 4)) + (q << 2)];
    }
    const uint32 tagq = 1023u ^ (uint32)((w << 6) | (q << 2));

    // ---- issue tile-1 z loads; they arrive during tile-0 GEMM ----
    float z1v[8];
    #pragma unroll
    for (int j = 0; j < 8; ++j)
        z1v[j] = __builtin_nontemporal_load(&z[zoff0 + 128 + (cg * 8 + j) * HWALL + r]);

    // ---- stage tile-0 -> Abf (bf16, pitch 72) ----
    {
        ushort4v pk0, pk1;
        #pragma unroll
        for (int j = 0; j < 4; ++j) { pk0[j] = f2bf(z0v[j]); pk1[j] = f2bf(z0v[4 + j]); }
        *(ushort4v*)&Abf[r * 72 + cg * 8]     = pk0;
        *(ushort4v*)&Abf[r * 72 + cg * 8 + 4] = pk1;
    }
    __syncthreads();

    float lsum = 0.f;

    // GEMM: lane (q,m), reg rr holds C[code=(w4+j)*16+q*4+rr][zrow=mbb*16+m];
    // argmax over codes = in-reg fmax (j,rr) + xor16/xor32 across q-lanes.
    auto do_gemm = [&]() {
        float best[8];
        #pragma unroll
        for (int i = 0; i < 8; ++i) best[i] = -__builtin_inff();
        #pragma unroll
        for (int mbb = 0; mbb < 8; ++mbb) {
            bf16x8 a0 = *(const bf16x8*)&Abf[(mbb * 16 + m) * 72 + (q << 3)];
            bf16x8 a1 = *(const bf16x8*)&Abf[(mbb * 16 + m) * 72 + 32 + (q << 3)];
            #pragma unroll
            for (int j = 0; j < 4; ++j) {
                const uint32 tb = tagq ^ (uint32)(j << 4);
                f32x4 acc = nbv[j];
                acc = __builtin_amdgcn_mfma_f32_16x16x32_bf16(Bv[j][0], a0, acc, 0, 0, 0);
                acc = __builtin_amdgcn_mfma_f32_16x16x32_bf16(Bv[j][1], a1, acc, 0, 0, 0);
                #pragma unroll
                for (int rr = 0; rr < 4; ++rr) {
                    uint32 kb = (__builtin_bit_cast(uint32, acc[rr]) & 0xFFFFFC00u)
                              | (tb ^ (uint32)rr);
                    best[mbb] = fmaxf(best[mbb], __builtin_bit_cast(float, kb));
                }
            }
        }
        #pragma unroll
        for (int mb = 0; mb < 8; ++mb) {
            float v = best[mb];
            v = fmaxf(v, __shfl_xor(v, 16, 64));
            v = fmaxf(v, __shfl_xor(v, 32, 64));
            if (l < 16) partial[w][mb * 16 + m] = v;   // l<16 => q==0, m==l
        }
    };

    // tree-combine the 16 per-wave keys for row r
    auto combine = [&](float& km) {
        float pv[16];
        #pragma unroll
        for (int j = 0; j < 16; ++j) pv[j] = partial[j][r];
        #pragma unroll
        for (int s = 8; s; s >>= 1)
            #pragma unroll
            for (int j = 0; j < s; ++j) pv[j] = fmaxf(pv[j], pv[j + s]);
        km = pv[0];
    };

    // ================= tile 0 =================
    do_gemm();
    __syncthreads();

    // combine + issue gather (bf16 codebook, 2x8B); latency hides under restage
    ushort4v ec0, ec1;
    {
        float km; combine(km);
        int idx0 = 1023 - (int)(__builtin_bit_cast(uint32, km) & 1023u);
        ec0 = *(const ushort4v*)&cbb[(idx0 << 6) + (cg << 3)];
        ec1 = *(const ushort4v*)&cbb[(idx0 << 6) + (cg << 3) + 4];
    }

    // restage tile-1 (tile-0 zp lives in z0v regs, Abf free to overwrite)
    {
        ushort4v pk0, pk1;
        #pragma unroll
        for (int j = 0; j < 4; ++j) { pk0[j] = f2bf(z1v[j]); pk1[j] = f2bf(z1v[4 + j]); }
        *(ushort4v*)&Abf[r * 72 + cg * 8]     = pk0;
        *(ushort4v*)&Abf[r * 72 + cg * 8 + 4] = pk1;
    }
    __syncthreads();

    // consume tile-0: NT stores stream to HBM without allocating L2 lines
    #pragma unroll
    for (int j = 0; j < 4; ++j) {
        float v0 = __builtin_bit_cast(float, (uint32)ec0[j] << 16);
        float v1 = __builtin_bit_cast(float, (uint32)ec1[j] << 16);
        __builtin_nontemporal_store(v0, &out[1 + zoff0 + (cg * 8 + j) * HWALL + r]);
        __builtin_nontemporal_store(v1, &out[1 + zoff0 + (cg * 8 + 4 + j) * HWALL + r]);
        float d0 = v0 - z0v[j], d1 = v1 - z0v[4 + j];
        lsum += d0 * d0 + d1 * d1;
    }

    // ================= tile 1 =================
    do_gemm();
    __syncthreads();

    {
        float km; combine(km);
        int idx1 = 1023 - (int)(__builtin_bit_cast(uint32, km) & 1023u);
        ushort4v f0 = *(const ushort4v*)&cbb[(idx1 << 6) + (cg << 3)];
        ushort4v f1 = *(const ushort4v*)&cbb[(idx1 << 6) + (cg << 3) + 4];
        #pragma unroll
        for (int j = 0; j < 4; ++j) {
            float v0 = __builtin_bit_cast(float, (uint32)f0[j] << 16);
            float v1 = __builtin_bit_cast(float, (uint32)f1[j] << 16);
            __builtin_nontemporal_store(v0, &out[1 + zoff0 + 128 + (cg * 8 + j) * HWALL + r]);
            __builtin_nontemporal_store(v1, &out[1 + zoff0 + 128 + (cg * 8 + 4 + j) * HWALL + r]);
            float d0 = v0 - z1v[j], d1 = v1 - z1v[4 + j];
            lsum += d0 * d0 + d1 * d1;
        }
    }

    // ---- loss: wave reduce -> LDS -> one global atomic per block ----
    #pragma unroll
    for (int d = 1; d < 64; d <<= 1) lsum += __shfl_xor(lsum, d, 64);
    if (l == 0) atomicAdd(&loss_acc, lsum);
    __syncthreads();
    if (t == 0) atomicAdd(out, loss_acc * (1.25f / 4194304.f));  // (1+BETA)/numel
}

extern "C" void kernel_launch(void* const* d_in, const int* in_sizes, int n_in,
                              void* d_out, int out_size, void* d_ws, size_t ws_size,
                              hipStream_t stream) {
    (void)in_sizes; (void)n_in; (void)out_size; (void)ws_size;
    const float* z  = (const float*)d_in[0];
    const float* cb = (const float*)d_in[1];
    float* out = (float*)d_out;
    ushort* cbb = (ushort*)d_ws;
    float* negbias = (float*)((char*)d_ws + K_CODES * CDIM * sizeof(ushort));

    prep_kernel<<<dim3(256), dim3(256), 0, stream>>>(cb, cbb, negbias, out);
    vq_kernel<<<dim3(256), dim3(1024), 0, stream>>>(z, cbb, negbias, out);
}

// Round 4
// 129.754 us; speedup vs baseline: 1.0074x; 1.0074x over previous
//
#include <hip/hip_runtime.h>

typedef unsigned int uint32;
typedef unsigned short ushort;

typedef __bf16  bf16x8   __attribute__((ext_vector_type(8)));
typedef float   f32x4    __attribute__((ext_vector_type(4)));
typedef ushort  ushort4v __attribute__((ext_vector_type(4)));
typedef ushort  ushort8v __attribute__((ext_vector_type(8)));

#define K_CODES 1024
#define CDIM    64
#define HWALL   4096      // H*W
#define CHW     262144    // CDIM*HWALL
#define TROWS   128       // z-rows per tile (2 tiles per block)

__device__ __forceinline__ ushort f2bf(float f) {
    uint32 u = __builtin_bit_cast(uint32, f);
    u += 0x7FFFu + ((u >> 16) & 1u);   // RNE
    return (ushort)(u >> 16);
}

// Pass 0 (tiny, coalesced): codebook fp32 -> bf16 row-major + negbias[k] =
// -0.5*||e_k||^2. Also zeroes the loss cell out[0].
__global__ __launch_bounds__(256) void prep_kernel(const float* __restrict__ cb,
                                                   ushort* __restrict__ cbb,
                                                   float* __restrict__ negbias,
                                                   float* __restrict__ out) {
    int t = threadIdx.x;
    if (blockIdx.x == 0 && t == 0) out[0] = 0.f;
    int k = blockIdx.x * 4 + (t >> 6);
    int c = t & 63;
    float v = cb[k * 64 + c];
    cbb[k * 64 + c] = f2bf(v);
    float s = v * v;
    #pragma unroll
    for (int d = 1; d < 64; d <<= 1) s += __shfl_xor(s, d, 64);
    if (c == 0) negbias[k] = -0.5f * s;
}

// Main: 256 blocks (1/CU) x 1024 threads (16 waves), two 128-row tiles.
// R12: swapped MFMA operands (argmax mostly in-register).
// R13: NT loads/stores for the z/out streams (neutral on traffic, kept to
//      protect codebook L2 residency).
// R14 change: COALESCED CODEBOOK GATHER. R2/R3 counters: FETCH 84.3 MB =
// 16.8 (z) + ~64 (gather line-misses) -- the old gather had 64 consecutive
// lanes reading 64 random codebook rows (one cache line each, ~1M line
// transactions total). New scheme: wave w, lane l gathers row w*8+(l>>3),
// 16B chunk l&7 -> 8 contiguous 128B segments per wave instruction (8x fewer
// lines, 1 instr instead of 2), redistributed via padded LDS (vqb) back to
// the (r,cg) threads that own the coalesced out stores + loss. Tile-0 gather
// latency hides under the tile-1 restage.
__global__ __launch_bounds__(1024, 4) void vq_kernel(const float* __restrict__ z,
                                                     const ushort* __restrict__ cbb,
                                                     const float* __restrict__ negbias,
                                                     float* __restrict__ out) {
    __shared__ __align__(16) ushort Abf[TROWS * 72];  // 18 KB A-tile, pitch 72
    __shared__ __align__(16) ushort vqb[TROWS * 72];  // 18 KB gathered vq rows
    __shared__ float partial[16][TROWS];              // 8 KB packed argmax keys
    __shared__ int   sidx[TROWS];                     // argmin index per row
    __shared__ float loss_acc;

    const int t   = threadIdx.x;
    const int blk = blockIdx.x;
    const int b   = blk >> 4;
    const int hw0 = (blk & 15) << 8;          // 256 rows per block
    const int zoff0 = b * CHW + hw0;

    if (t == 0) loss_acc = 0.f;

    const int r  = t & 127;    // z-row within tile (lanes consecutive -> coalesced)
    const int cg = t >> 7;     // c-group 0..7
    const int w  = t >> 6;     // wave 0..15: owns codes [w*64, +64)
    const int l  = t & 63;
    const int m  = l & 15;
    const int q  = l >> 4;
    const int grow = (w << 3) + (l >> 3);     // gather row for this lane
    const int gch  = l & 7;                   // gather 16B chunk

    // ---- issue tile-0 z loads (deepest dep); NT: streamed once ----
    float z0v[8];
    #pragma unroll
    for (int j = 0; j < 8; ++j)
        z0v[j] = __builtin_nontemporal_load(&z[zoff0 + (cg * 8 + j) * HWALL + r]);

    // ---- load this wave's codebook slice into registers (once, from bf16) ----
    bf16x8 Bv[4][2];
    f32x4  nbv[4];
    #pragma unroll
    for (int j = 0; j < 4; ++j) {
        int col = (((w << 2) + j) << 4) + m;
        Bv[j][0] = *(const bf16x8*)&cbb[(col << 6) + (q << 3)];
        Bv[j][1] = *(const bf16x8*)&cbb[(col << 6) + 32 + (q << 3)];
        nbv[j] = *(const f32x4*)&negbias[((((w << 2) + j) << 4)) + (q << 2)];
    }
    const uint32 tagq = 1023u ^ (uint32)((w << 6) | (q << 2));

    // ---- issue tile-1 z loads; they arrive during tile-0 GEMM ----
    float z1v[8];
    #pragma unroll
    for (int j = 0; j < 8; ++j)
        z1v[j] = __builtin_nontemporal_load(&z[zoff0 + 128 + (cg * 8 + j) * HWALL + r]);

    // ---- stage tile-0 -> Abf (bf16, pitch 72) ----
    {
        ushort4v pk0, pk1;
        #pragma unroll
        for (int j = 0; j < 4; ++j) { pk0[j] = f2bf(z0v[j]); pk1[j] = f2bf(z0v[4 + j]); }
        *(ushort4v*)&Abf[r * 72 + cg * 8]     = pk0;
        *(ushort4v*)&Abf[r * 72 + cg * 8 + 4] = pk1;
    }
    __syncthreads();

    float lsum = 0.f;

    // GEMM: lane (q,m), reg rr holds C[code=(w4+j)*16+q*4+rr][zrow=mbb*16+m];
    // argmax over codes = in-reg fmax (j,rr) + xor16/xor32 across q-lanes.
    auto do_gemm = [&]() {
        float best[8];
        #pragma unroll
        for (int i = 0; i < 8; ++i) best[i] = -__builtin_inff();
        #pragma unroll
        for (int mbb = 0; mbb < 8; ++mbb) {
            bf16x8 a0 = *(const bf16x8*)&Abf[(mbb * 16 + m) * 72 + (q << 3)];
            bf16x8 a1 = *(const bf16x8*)&Abf[(mbb * 16 + m) * 72 + 32 + (q << 3)];
            #pragma unroll
            for (int j = 0; j < 4; ++j) {
                const uint32 tb = tagq ^ (uint32)(j << 4);
                f32x4 acc = nbv[j];
                acc = __builtin_amdgcn_mfma_f32_16x16x32_bf16(Bv[j][0], a0, acc, 0, 0, 0);
                acc = __builtin_amdgcn_mfma_f32_16x16x32_bf16(Bv[j][1], a1, acc, 0, 0, 0);
                #pragma unroll
                for (int rr = 0; rr < 4; ++rr) {
                    uint32 kb = (__builtin_bit_cast(uint32, acc[rr]) & 0xFFFFFC00u)
                              | (tb ^ (uint32)rr);
                    best[mbb] = fmaxf(best[mbb], __builtin_bit_cast(float, kb));
                }
            }
        }
        #pragma unroll
        for (int mb = 0; mb < 8; ++mb) {
            float v = best[mb];
            v = fmaxf(v, __shfl_xor(v, 16, 64));
            v = fmaxf(v, __shfl_xor(v, 32, 64));
            if (l < 16) partial[w][mb * 16 + m] = v;   // l<16 => q==0, m==l
        }
    };

    // combine (threads t<128 only, one per row): tree-max of 16 wave keys
    auto combine_store_idx = [&]() {
        if (t < 128) {
            float pv[16];
            #pragma unroll
            for (int j = 0; j < 16; ++j) pv[j] = partial[j][t];
            #pragma unroll
            for (int s = 8; s; s >>= 1)
                #pragma unroll
                for (int j = 0; j < s; ++j) pv[j] = fmaxf(pv[j], pv[j + s]);
            sidx[t] = 1023 - (int)(__builtin_bit_cast(uint32, pv[0]) & 1023u);
        }
    };

    // ================= tile 0 =================
    do_gemm();
    __syncthreads();                      // B1: partial ready
    combine_store_idx();
    __syncthreads();                      // B2: sidx ready

    // coalesced gather: 8 contiguous 128B codebook rows per wave instruction
    ushort8v gv0 = *(const ushort8v*)&cbb[(sidx[grow] << 6) + (gch << 3)];

    // restage tile-1 while the gather is in flight
    {
        ushort4v pk0, pk1;
        #pragma unroll
        for (int j = 0; j < 4; ++j) { pk0[j] = f2bf(z1v[j]); pk1[j] = f2bf(z1v[4 + j]); }
        *(ushort4v*)&Abf[r * 72 + cg * 8]     = pk0;
        *(ushort4v*)&Abf[r * 72 + cg * 8 + 4] = pk1;
    }
    *(ushort8v*)&vqb[grow * 72 + gch * 8] = gv0;
    __syncthreads();                      // B3: vqb + Abf ready

    // consume tile-0: redistribute vq from LDS, NT-store + loss
    {
        ushort8v ev = *(const ushort8v*)&vqb[r * 72 + cg * 8];
        #pragma unroll
        for (int j = 0; j < 4; ++j) {
            float v0 = __builtin_bit_cast(float, (uint32)ev[j] << 16);
            float v1 = __builtin_bit_cast(float, (uint32)ev[4 + j] << 16);
            __builtin_nontemporal_store(v0, &out[1 + zoff0 + (cg * 8 + j) * HWALL + r]);
            __builtin_nontemporal_store(v1, &out[1 + zoff0 + (cg * 8 + 4 + j) * HWALL + r]);
            float d0 = v0 - z0v[j], d1 = v1 - z0v[4 + j];
            lsum += d0 * d0 + d1 * d1;
        }
    }

    // ================= tile 1 =================
    do_gemm();
    __syncthreads();                      // B1'
    combine_store_idx();
    __syncthreads();                      // B2'

    {
        ushort8v gv1 = *(const ushort8v*)&cbb[(sidx[grow] << 6) + (gch << 3)];
        *(ushort8v*)&vqb[grow * 72 + gch * 8] = gv1;
    }
    __syncthreads();                      // B3'

    {
        ushort8v ev = *(const ushort8v*)&vqb[r * 72 + cg * 8];
        #pragma unroll
        for (int j = 0; j < 4; ++j) {
            float v0 = __builtin_bit_cast(float, (uint32)ev[j] << 16);
            float v1 = __builtin_bit_cast(float, (uint32)ev[4 + j] << 16);
            __builtin_nontemporal_store(v0, &out[1 + zoff0 + 128 + (cg * 8 + j) * HWALL + r]);
            __builtin_nontemporal_store(v1, &out[1 + zoff0 + 128 + (cg * 8 + 4 + j) * HWALL + r]);
            float d0 = v0 - z1v[j], d1 = v1 - z1v[4 + j];
            lsum += d0 * d0 + d1 * d1;
        }
    }

    // ---- loss: wave reduce -> LDS -> one global atomic per block ----
    #pragma unroll
    for (int d = 1; d < 64; d <<= 1) lsum += __shfl_xor(lsum, d, 64);
    if (l == 0) atomicAdd(&loss_acc, lsum);
    __syncthreads();
    if (t == 0) atomicAdd(out, loss_acc * (1.25f / 4194304.f));  // (1+BETA)/numel
}

extern "C" void kernel_launch(void* const* d_in, const int* in_sizes, int n_in,
                              void* d_out, int out_size, void* d_ws, size_t ws_size,
                              hipStream_t stream) {
    (void)in_sizes; (void)n_in; (void)out_size; (void)ws_size;
    const float* z  = (const float*)d_in[0];
    const float* cb = (const float*)d_in[1];
    float* out = (float*)d_out;
    ushort* cbb = (ushort*)d_ws;
    float* negbias = (float*)((char*)d_ws + K_CODES * CDIM * sizeof(ushort));

    prep_kernel<<<dim3(256), dim3(256), 0, stream>>>(cb, cbb, negbias, out);
    vq_kernel<<<dim3(256), dim3(1024), 0, stream>>>(z, cbb, negbias, out);
}

// Round 5
// 86.087 us; speedup vs baseline: 1.5184x; 1.5072x over previous
//
#include <hip/hip_runtime.h>

typedef unsigned int uint32;
typedef unsigned short ushort;

typedef __bf16  bf16x8   __attribute__((ext_vector_type(8)));
typedef float   f32x4    __attribute__((ext_vector_type(4)));
typedef ushort  ushort4v __attribute__((ext_vector_type(4)));

#define K_CODES 1024
#define CDIM    64
#define HWALL   4096      // H*W
#define CHW     262144    // CDIM*HWALL
#define TROWS   128       // z-rows per tile (2 tiles per block)

__device__ __forceinline__ ushort f2bf(float f) {
    uint32 u = __builtin_bit_cast(uint32, f);
    u += 0x7FFFu + ((u >> 16) & 1u);   // RNE
    return (ushort)(u >> 16);
}

// Pass 0 (tiny, coalesced): codebook fp32 -> bf16 row-major + negbias[k] =
// -0.5*||e_k||^2. Also zeroes the loss cell out[0].
// (R9 lesson: fusing this into vq_kernel makes the fp32 B loads lane-strided
//  256B/uncoalesced -- keep the separate dispatch.)
__global__ __launch_bounds__(256) void prep_kernel(const float* __restrict__ cb,
                                                   ushort* __restrict__ cbb,
                                                   float* __restrict__ negbias,
                                                   float* __restrict__ out) {
    int t = threadIdx.x;
    if (blockIdx.x == 0 && t == 0) out[0] = 0.f;
    int k = blockIdx.x * 4 + (t >> 6);
    int c = t & 63;
    float v = cb[k * 64 + c];
    cbb[k * 64 + c] = f2bf(v);
    float s = v * v;
    #pragma unroll
    for (int d = 1; d < 64; d <<= 1) s += __shfl_xor(s, d, 64);
    if (c == 0) negbias[k] = -0.5f * s;
}

// R15 = EXACT REVERT to the R0 baseline artifact (86.7 us session-best).
// Rationale: R2-R4 (operand-swap family) all measured vq at 65-67 us while
// the harness poison-fills still ran at ~43 us (containers healthy), so the
// swap family is a real ~23 us regression vs baseline vq <= 43 us. Three
// traffic theories (shuffle pressure, write-allocate, gather lines) were
// all falsified by unmoved FETCH/WRITE counters (~251 MB, invariant).
// This round re-anchors attribution: same code as R0, single variable.
__global__ __launch_bounds__(1024, 4) void vq_kernel(const float* __restrict__ z,
                                                     const ushort* __restrict__ cbb,
                                                     const float* __restrict__ negbias,
                                                     float* __restrict__ out) {
    __shared__ __align__(16) ushort Abf[TROWS * 72];  // 18 KB A-tile, pitch 72
    __shared__ float partial[16][TROWS];              // 8 KB packed argmax keys
    __shared__ float loss_acc;

    const int t   = threadIdx.x;
    const int blk = blockIdx.x;
    const int b   = blk >> 4;
    const int hw0 = (blk & 15) << 8;          // 256 rows per block
    const int zoff0 = b * CHW + hw0;

    if (t == 0) loss_acc = 0.f;

    const int r  = t & 127;    // z-row within tile (lanes consecutive -> coalesced)
    const int cg = t >> 7;     // c-group 0..7
    const int w  = t >> 6;     // wave 0..15: owns n-tiles [w*4, +4)
    const int l  = t & 63;
    const int m  = l & 15;     // B col within n-tile / A row within m-block
    const int q  = l >> 4;     // k-quad

    // ---- issue tile-0 z loads (deepest dep) ----
    float z0v[8];
    #pragma unroll
    for (int j = 0; j < 8; ++j) z0v[j] = z[zoff0 + (cg * 8 + j) * HWALL + r];

    // ---- load this wave's codebook slice into registers (once, from bf16) ----
    bf16x8 Bv[4][2];
    float  nb[4];
    #pragma unroll
    for (int j = 0; j < 4; ++j) {
        int col = (((w << 2) + j) << 4) + m;
        Bv[j][0] = *(const bf16x8*)&cbb[(col << 6) + (q << 3)];
        Bv[j][1] = *(const bf16x8*)&cbb[(col << 6) + 32 + (q << 3)];
        nb[j] = negbias[col];
    }

    // ---- issue tile-1 z loads; they arrive during tile-0 GEMM ----
    float z1v[8];
    #pragma unroll
    for (int j = 0; j < 8; ++j) z1v[j] = z[zoff0 + 128 + (cg * 8 + j) * HWALL + r];

    // ---- stage tile-0 -> Abf (bf16, pitch 72) ----
    {
        ushort4v pk0, pk1;
        #pragma unroll
        for (int j = 0; j < 4; ++j) { pk0[j] = f2bf(z0v[j]); pk1[j] = f2bf(z0v[4 + j]); }
        *(ushort4v*)&Abf[r * 72 + cg * 8]     = pk0;
        *(ushort4v*)&Abf[r * 72 + cg * 8 + 4] = pk1;
    }
    __syncthreads();

    float lsum = 0.f;

    // GEMM over current Abf: 8 m-blocks x this wave's 4 n-tiles (reg-B),
    // packed-key argmax -> partial[w][0..127].
    auto do_gemm = [&]() {
        float best[16];
        #pragma unroll
        for (int i = 0; i < 16; ++i) best[i] = -__builtin_inff();
        #pragma unroll
        for (int mbb = 0; mbb < 8; ++mbb) {
            bf16x8 a0 = *(const bf16x8*)&Abf[(mbb * 16 + m) * 72 + (q << 3)];
            bf16x8 a1 = *(const bf16x8*)&Abf[(mbb * 16 + m) * 72 + 32 + (q << 3)];
            #pragma unroll
            for (int j = 0; j < 4; ++j) {
                uint32 tag = 1023u - (uint32)(((((w << 2) + j) << 4)) + m);
                f32x4 acc0;
                acc0[0] = nb[j]; acc0[1] = nb[j]; acc0[2] = nb[j]; acc0[3] = nb[j];
                f32x4 acc = __builtin_amdgcn_mfma_f32_16x16x32_bf16(a0, Bv[j][0], acc0, 0, 0, 0);
                acc       = __builtin_amdgcn_mfma_f32_16x16x32_bf16(a1, Bv[j][1], acc,  0, 0, 0);
                #pragma unroll
                for (int rr = 0; rr < 4; ++rr) {
                    uint32 kb = (__builtin_bit_cast(uint32, acc[rr]) & 0xFFFFFC00u) | tag;
                    int bi = (mbb & 3) * 4 + rr;
                    best[bi] = fmaxf(best[bi], __builtin_bit_cast(float, kb));
                }
            }
            if ((mbb & 3) == 3) {   // checkpoint: reduce + store 4 m-blocks
                #pragma unroll
                for (int i = 0; i < 16; ++i) {
                    float v = best[i];
                    #pragma unroll
                    for (int d = 1; d < 16; d <<= 1) v = fmaxf(v, __shfl_xor(v, d, 64));
                    best[i] = v;
                }
                if (m == 0) {
                    int base = (mbb - 3) * 16;
                    #pragma unroll
                    for (int mb2 = 0; mb2 < 4; ++mb2)
                        #pragma unroll
                        for (int rr = 0; rr < 4; ++rr)
                            partial[w][base + mb2 * 16 + (q << 2) + rr] = best[mb2 * 4 + rr];
                }
                #pragma unroll
                for (int i = 0; i < 16; ++i) best[i] = -__builtin_inff();
            }
        }
    };

    // ================= tile 0 =================
    do_gemm();
    __syncthreads();

    // combine + issue gather (bf16 codebook, 2x8B); latency hides under restage
    ushort4v ec0, ec1;
    {
        float km = partial[0][r];
        #pragma unroll
        for (int j = 1; j < 16; ++j) km = fmaxf(km, partial[j][r]);
        int idx0 = 1023 - (int)(__builtin_bit_cast(uint32, km) & 1023u);
        ec0 = *(const ushort4v*)&cbb[(idx0 << 6) + (cg << 3)];
        ec1 = *(const ushort4v*)&cbb[(idx0 << 6) + (cg << 3) + 4];
    }

    // restage tile-1 (tile-0 zp lives in z0v regs, Abf free to overwrite)
    {
        ushort4v pk0, pk1;
        #pragma unroll
        for (int j = 0; j < 4; ++j) { pk0[j] = f2bf(z1v[j]); pk1[j] = f2bf(z1v[4 + j]); }
        *(ushort4v*)&Abf[r * 72 + cg * 8]     = pk0;
        *(ushort4v*)&Abf[r * 72 + cg * 8 + 4] = pk1;
    }
    __syncthreads();

    // consume tile-0: stores retire async while gemm1 runs on the MFMA pipe
    #pragma unroll
    for (int j = 0; j < 4; ++j) {
        float v0 = __builtin_bit_cast(float, (uint32)ec0[j] << 16);
        float v1 = __builtin_bit_cast(float, (uint32)ec1[j] << 16);
        out[1 + zoff0 + (cg * 8 + j) * HWALL + r]     = v0;   // ST fwd == vq
        out[1 + zoff0 + (cg * 8 + 4 + j) * HWALL + r] = v1;
        float d0 = v0 - z0v[j], d1 = v1 - z0v[4 + j];
        lsum += d0 * d0 + d1 * d1;
    }

    // ================= tile 1 =================
    do_gemm();
    __syncthreads();

    {
        float km = partial[0][r];
        #pragma unroll
        for (int j = 1; j < 16; ++j) km = fmaxf(km, partial[j][r]);
        int idx1 = 1023 - (int)(__builtin_bit_cast(uint32, km) & 1023u);
        ushort4v f0 = *(const ushort4v*)&cbb[(idx1 << 6) + (cg << 3)];
        ushort4v f1 = *(const ushort4v*)&cbb[(idx1 << 6) + (cg << 3) + 4];
        #pragma unroll
        for (int j = 0; j < 4; ++j) {
            float v0 = __builtin_bit_cast(float, (uint32)f0[j] << 16);
            float v1 = __builtin_bit_cast(float, (uint32)f1[j] << 16);
            out[1 + zoff0 + 128 + (cg * 8 + j) * HWALL + r]     = v0;
            out[1 + zoff0 + 128 + (cg * 8 + 4 + j) * HWALL + r] = v1;
            float d0 = v0 - z1v[j], d1 = v1 - z1v[4 + j];
            lsum += d0 * d0 + d1 * d1;
        }
    }

    // ---- loss: wave reduce -> LDS -> one global atomic per block ----
    #pragma unroll
    for (int d = 1; d < 64; d <<= 1) lsum += __shfl_xor(lsum, d, 64);
    if (l == 0) atomicAdd(&loss_acc, lsum);
    __syncthreads();
    if (t == 0) atomicAdd(out, loss_acc * (1.25f / 4194304.f));  // (1+BETA)/numel
}

extern "C" void kernel_launch(void* const* d_in, const int* in_sizes, int n_in,
                              void* d_out, int out_size, void* d_ws, size_t ws_size,
                              hipStream_t stream) {
    (void)in_sizes; (void)n_in; (void)out_size; (void)ws_size;
    const float* z  = (const float*)d_in[0];
    const float* cb = (const float*)d_in[1];
    float* out = (float*)d_out;
    ushort* cbb = (ushort*)d_ws;
    float* negbias = (float*)((char*)d_ws + K_CODES * CDIM * sizeof(ushort));

    prep_kernel<<<dim3(256), dim3(256), 0, stream>>>(cb, cbb, negbias, out);
    vq_kernel<<<dim3(256), dim3(1024), 0, stream>>>(z, cbb, negbias, out);
}